// Round 19
// baseline (3318.448 us; speedup 1.0000x reference)
//
#include <hip/hip_runtime.h>

typedef float f32x4 __attribute__((ext_vector_type(4)));
typedef float f32x16 __attribute__((ext_vector_type(16)));
typedef _Float16 f16x4 __attribute__((ext_vector_type(4)));
typedef long long i64t;

constexpr int T = 8192, H = 2048, II = 1024, E = 32, TOPK = 8;
constexpr int NSLOT = T * TOPK;
constexpr int NSLOT_P = NSLOT + E * 16 + 128;   // per-expert pad to 16 + slack
constexpr int MT_MAX = 32;        // 128-row blocks per expert (gemm2)
constexpr int MT1 = 64;           // 64-row blocks per expert (gemm1)

// async global->LDS, 16B per lane; LDS dest = wave-uniform base + lane*16
__device__ __forceinline__ void gload16(const unsigned char* g, unsigned char* l) {
  __builtin_amdgcn_global_load_lds((const __attribute__((address_space(1))) unsigned int*)g,
                                   (__attribute__((address_space(3))) unsigned int*)l, 16, 0, 0);
}

// ---------- LDS fp8 tile swizzle (rows x 128 bytes) ----------
// logical 8B chunk j of row r lives at physical 8B index j ^ ((r&7)<<1) ^ ((r>>3)&1).
__device__ __forceinline__ i64t frag8(const unsigned char* lds, int row, int kbyte) {
  int c8 = (kbyte >> 3) ^ ((row & 7) << 1) ^ ((row >> 3) & 1);
  return *(const i64t*)(lds + row * 128 + c8 * 8);
}
// store logical 16B chunk c of row r in swizzled image (16B XOR + 8B half-swap)
__device__ __forceinline__ void wr16c(unsigned char* lds, int r, int c, uint4 v) {
  if ((r >> 3) & 1) v = make_uint4(v.z, v.w, v.x, v.y);
  *(uint4*)(lds + r * 128 + ((c ^ (r & 7)) << 4)) = v;
}

// ---------- activation quantization (bit-exact vs reference) ----------
__global__ void k_quant_x(const float* __restrict__ x, unsigned char* __restrict__ x8,
                          float* __restrict__ xs) {
  int gw = blockIdx.x * 4 + (threadIdx.x >> 6);
  int lane = threadIdx.x & 63;
  int token = gw >> 4, kb = gw & 15;
  float2 v = *(const float2*)(x + (size_t)token * H + kb * 128 + lane * 2);
  float am = fmaxf(fabsf(v.x), fabsf(v.y));
#pragma unroll
  for (int m = 1; m <= 32; m <<= 1) am = fmaxf(am, __shfl_xor(am, m, 64));
  float scale = fmaxf(am, 1e-12f) / 448.0f;
  int pk = __builtin_amdgcn_cvt_pk_fp8_f32(v.x / scale, v.y / scale, 0, false);
  *(unsigned short*)(x8 + (size_t)token * H + kb * 128 + lane * 2) = (unsigned short)(pk & 0xffff);
  if (lane == 0) xs[token * 16 + kb] = scale;
}

// ---------- weight cast f32 -> fp8, stored in PRE-SWIZZLED (LDS-image) layout ----------
__global__ void k_cvt_w_sw(const float* __restrict__ w, unsigned char* __restrict__ w8,
                           int cpr /*16B chunks per row*/, int nchunk) {
  int i = blockIdx.x * 256 + threadIdx.x;
  if (i >= nchunk) return;
  int row = i / cpr;
  int within = i - row * cpr;
  int kb = within >> 3, pc = within & 7;
  int lc = pc ^ (row & 7);
  int sw = ((row >> 3) & 1) ? 8 : 0;
  const float* src = w + (size_t)row * ((size_t)cpr * 16) + kb * 128 + lc * 16;
  unsigned int o[4];
#pragma unroll
  for (int k = 0; k < 4; ++k) {
    int e0 = (4 * k + sw) & 15;
    f32x4 v = *(const f32x4*)(src + e0);
    int p = __builtin_amdgcn_cvt_pk_fp8_f32(v[0], v[1], 0, false);
    p = __builtin_amdgcn_cvt_pk_fp8_f32(v[2], v[3], p, true);
    o[k] = (unsigned int)p;
  }
  *(uint4*)(w8 + (size_t)i * 16) = make_uint4(o[0], o[1], o[2], o[3]);
}

// ---------- routing (per-expert ranges padded to 16 rows) ----------
__global__ void k_count(const int* __restrict__ tki, int* __restrict__ counts) {
  int i = blockIdx.x * 256 + threadIdx.x;
  if (i < NSLOT) atomicAdd(&counts[tki[i]], 1);
}
__global__ void k_scan(const int* __restrict__ counts, int* __restrict__ offsets) {
  if (threadIdx.x == 0) {
    int s = 0;
    for (int e = 0; e < E; ++e) { offsets[e] = s; s += ((counts[e] + 15) >> 4) << 4; }
    offsets[E] = s;
  }
}
__global__ void k_fill(const int* __restrict__ tki, const float* __restrict__ tkw,
                       const int* __restrict__ offsets, int* __restrict__ cursor,
                       int* __restrict__ tok_list, float* __restrict__ cw_list,
                       int* __restrict__ islot) {
  int i = blockIdx.x * 256 + threadIdx.x;
  if (i < NSLOT) {
    int e = tki[i];
    int pos = atomicAdd(&cursor[e], 1);
    int slot = offsets[e] + pos;
    tok_list[slot] = i >> 3;
    cw_list[slot] = tkw[i];
    islot[i] = slot;
  }
}

// ---------- GEMM1: m97-style single-buffer, 3 blocks/CU ----------
__launch_bounds__(256, 3)
__global__ void k_gemm1(const unsigned char* __restrict__ x8, const float* __restrict__ xs,
                        const unsigned char* __restrict__ wgu8, const float* __restrict__ sgu,
                        const int* __restrict__ offsets, const int* __restrict__ counts,
                        const int* __restrict__ tok_list,
                        unsigned char* __restrict__ a8, float* __restrict__ ascale) {
  __shared__ __align__(16) unsigned char lA[64 * 128];     // 8 KB
  __shared__ __align__(16) unsigned char lBg[128 * 128];   // 16 KB
  __shared__ __align__(16) unsigned char lBu[128 * 128];   // 16 KB
  __shared__ float lsx[16 * 64];    // 4 KB
  __shared__ int ltok[64];
  __shared__ float lamax[64 * 2];
  __shared__ float lscale[64];

  int bx = blockIdx.x;
  int e = bx >> 9, mt = (bx >> 3) & 63, nt = bx & 7;
  int off0 = offsets[e];
  int Me = counts[e];
  if (mt * 64 >= Me) return;
  int vrows = Me - mt * 64; if (vrows > 64) vrows = 64;
  int tid = threadIdx.x;

  if (tid < 64) ltok[tid] = (tid < vrows) ? tok_list[off0 + mt * 64 + tid] : -1;
  __syncthreads();

  if (tid < 128) {  // stage x scales transposed: lsx[kb][row]
    int r = tid >> 1, h = tid & 1;
    int tokr = ltok[r]; int tk = tokr < 0 ? 0 : tokr;
#pragma unroll
    for (int i = 0; i < 2; ++i) {
      f32x4 v = *(const f32x4*)(xs + (size_t)tk * 16 + h * 8 + i * 4);
#pragma unroll
      for (int j = 0; j < 4; ++j) lsx[(h * 8 + i * 4 + j) * 64 + r] = (tokr < 0) ? 0.0f : v[j];
    }
  }

  const int lane = tid & 63, wid = tid >> 6;
  const int wm = wid >> 1, wn = wid & 1;
  const int l31 = lane & 31, lg = lane >> 5;

  // A staging (register path, token-gathered; LDS-image via wr16c)
  const int ra = tid >> 2, qa = tid & 3;
  int tokA = ltok[ra] < 0 ? 0 : ltok[ra];
  const unsigned char* gA = x8 + (size_t)tokA * H + qa * 32;

  // B staging via gload_lds from PRE-SWIZZLED wgu8: linear lane->addr, linear LDS
  const int lr = lane >> 3, lc8 = lane & 7;
  const unsigned char* pG[4];
  const unsigned char* pU[4];
#pragma unroll
  for (int i = 0; i < 4; ++i) {
    int row = wid * 32 + i * 8 + lr;
    pG[i] = wgu8 + ((size_t)e * 2048 + nt * 128 + row) * H + lc8 * 16;
    pU[i] = pG[i] + (size_t)1024 * H;
  }

  f32x16 aG[2] = {};
  f32x16 aU[2] = {};

  for (int kb = 0; kb < 16; ++kb) {
    // A loads issued first (oldest in vmcnt queue; overlap barrier wait)
    uint4 va0 = *(const uint4*)(gA + kb * 128);
    uint4 va1 = *(const uint4*)(gA + kb * 128 + 16);
    __syncthreads();   // readers of previous tiles done
#pragma unroll
    for (int i = 0; i < 4; ++i) {
      gload16(pG[i] + kb * 128, lBg + wid * 4096 + i * 1024);
      gload16(pU[i] + kb * 128, lBu + wid * 4096 + i * 1024);
    }
    // wr16c waits only the A loads (B gloads newer in queue)
    wr16c(lA, ra, qa * 2 + 0, va0);
    wr16c(lA, ra, qa * 2 + 1, va1);
    __syncthreads();   // drain: B arrived, lA visible

    float swg = sgu[(e * 16 + nt) * 16 + kb];
    float swu = sgu[(e * 16 + 8 + nt) * 16 + kb];

    i64t af[8];
#pragma unroll
    for (int ks = 0; ks < 8; ++ks)
      af[ks] = frag8(lA, wm * 32 + l31, ks * 16 + lg * 8);
    f32x4 sxv[4];
#pragma unroll
    for (int jj = 0; jj < 4; ++jj)
      sxv[jj] = *(const f32x4*)(&lsx[kb * 64 + wm * 32 + jj * 8 + lg * 4]);

#pragma unroll
    for (int gu = 0; gu < 2; ++gu) {
      const unsigned char* lB = gu ? lBu : lBg;
      float sw = gu ? swu : swg;
#pragma unroll
      for (int nf = 0; nf < 2; ++nf) {
        i64t bf[8];
#pragma unroll
        for (int ks = 0; ks < 8; ++ks)
          bf[ks] = frag8(lB, wn * 64 + nf * 32 + l31, ks * 16 + lg * 8);
        f32x16 t = {};
#pragma unroll
        for (int ks = 0; ks < 8; ++ks)
          t = __builtin_amdgcn_mfma_f32_32x32x16_fp8_fp8(af[ks], bf[ks], t, 0, 0, 0);
#pragma unroll
        for (int j = 0; j < 16; ++j) {
          float f = sxv[j >> 2][j & 3] * sw;
          if (gu) aU[nf][j] += t[j] * f; else aG[nf][j] += t[j] * f;
        }
      }
    }
  }

  // silu(gate) * up -> aG
#pragma unroll
  for (int nf = 0; nf < 2; ++nf)
#pragma unroll
    for (int j = 0; j < 16; ++j) {
      float g = aG[nf][j], u = aU[nf][j];
      aG[nf][j] = g * (1.0f / (1.0f + expf(-g))) * u;
    }

  // per-row amax over the 128-col quant block
#pragma unroll
  for (int j = 0; j < 16; ++j) {
    float m = fmaxf(fabsf(aG[0][j]), fabsf(aG[1][j]));
#pragma unroll
    for (int msk = 1; msk <= 16; msk <<= 1) m = fmaxf(m, __shfl_xor(m, msk, 64));
    if (l31 == 0)
      lamax[(wm * 32 + (j & 3) + ((j >> 2) * 8) + lg * 4) * 2 + wn] = m;
  }
  __syncthreads();
  if (tid < 64) {
    float mm = fmaxf(lamax[tid * 2], lamax[tid * 2 + 1]);
    lscale[tid] = fmaxf(mm, 1e-12f) / 448.0f;
  }
  __syncthreads();   // lA dead -> reuse as byte staging

  // quantize into lA in PRE-SWIZZLED image (a8 stays gload_lds-ready for gemm2)
#pragma unroll
  for (int j = 0; j < 16; ++j) {
    int row = wm * 32 + (j & 3) + ((j >> 2) * 8) + lg * 4;
    float sc = lscale[row];
    int hs = ((row >> 3) & 1) ? 8 : 0;
#pragma unroll
    for (int nf = 0; nf < 2; ++nf) {
      int col = wn * 64 + nf * 32 + l31;
      int pk = __builtin_amdgcn_cvt_pk_fp8_f32(aG[nf][j] / sc, 0.0f, 0, false);
      lA[row * 128 + (((col >> 4) ^ (row & 7)) << 4) + ((col & 15) ^ hs)] = (unsigned char)(pk & 0xff);
    }
    if (row < vrows && l31 == 0 && wn == 0)
      ascale[(off0 + mt * 64 + row) * 8 + nt] = sc;
  }
  __syncthreads();
#pragma unroll
  for (int it = 0; it < 2; ++it) {
    int idx = it * 256 + tid;
    int row = idx >> 3, c = idx & 7;
    if (row < vrows)
      *(uint4*)(a8 + (size_t)(off0 + mt * 64 + row) * 1024 + nt * 128 + c * 16) =
          *(const uint4*)(lA + row * 128 + c * 16);
  }
}

// ---------- GEMM2 half-pass: m97-style single-buffer, 3 blocks/CU, f16 yslot ----------
__launch_bounds__(256, 3)
__global__ void k_gemm2(const unsigned char* __restrict__ a8, const float* __restrict__ ascale,
                        const unsigned char* __restrict__ wd8, const float* __restrict__ sd,
                        const int* __restrict__ offsets, const int* __restrict__ counts,
                        const float* __restrict__ cw_list,
                        int ntbase, _Float16* __restrict__ yslot) {
  __shared__ __align__(16) unsigned char lbuf[2][128 * 128];   // A,B = 32 KB
  __shared__ float las[8 * 128];
  __shared__ float lcw[128];

  int bx = blockIdx.x;
  int e = bx >> 8, mt = (bx >> 3) & 31, nth = bx & 7;
  int nt = ntbase + nth;
  int off0 = offsets[e];
  int Me = counts[e];
  if (mt * 128 >= Me) return;
  int vrows = Me - mt * 128; if (vrows > 128) vrows = 128;
  int tid = threadIdx.x;
  const int rowbase = off0 + mt * 128;

  if (tid < 128) lcw[tid] = (tid < vrows) ? cw_list[rowbase + tid] : 0.0f;
  {
    int r = tid >> 1, h = tid & 1;
    int srow = rowbase + r; if (srow > NSLOT_P - 1) srow = NSLOT_P - 1;
    f32x4 v = *(const f32x4*)(ascale + (size_t)srow * 8 + h * 4);
#pragma unroll
    for (int j = 0; j < 4; ++j) las[(h * 4 + j) * 128 + r] = v[j];
  }

  const int lane = tid & 63, wid = tid >> 6;
  const int wm = wid >> 1, wn = wid & 1;
  const int l31 = lane & 31, lg = lane >> 5;

  const int lr = lane >> 3, lc8 = lane & 7;
  const unsigned char* pA[4];
  const unsigned char* pB[4];
#pragma unroll
  for (int i = 0; i < 4; ++i) {
    int row = wid * 32 + i * 8 + lr;
    pA[i] = a8 + (size_t)(rowbase + row) * 1024 + lc8 * 16;
    pB[i] = wd8 + ((size_t)e * 2048 + nt * 128 + row) * 1024 + lc8 * 16;
  }

  f32x16 acc[2][2] = {};

  for (int kb = 0; kb < 8; ++kb) {
    __syncthreads();   // readers of previous tiles done (first: las/lcw visible)
#pragma unroll
    for (int i = 0; i < 4; ++i) {
      gload16(pA[i] + kb * 128, lbuf[0] + wid * 4096 + i * 1024);
      gload16(pB[i] + kb * 128, lbuf[1] + wid * 4096 + i * 1024);
    }
    __syncthreads();   // drain: tiles ready

    const unsigned char* cA = lbuf[0];
    const unsigned char* cB = lbuf[1];
    float swd = sd[(e * 16 + nt) * 8 + kb];
    i64t bf[2][8];
#pragma unroll
    for (int nf = 0; nf < 2; ++nf)
#pragma unroll
      for (int ks = 0; ks < 8; ++ks)
        bf[nf][ks] = frag8(cB, wn * 64 + nf * 32 + l31, ks * 16 + lg * 8);
#pragma unroll
    for (int mf = 0; mf < 2; ++mf) {
      i64t af[8];
#pragma unroll
      for (int ks = 0; ks < 8; ++ks)
        af[ks] = frag8(cA, wm * 64 + mf * 32 + l31, ks * 16 + lg * 8);
      f32x4 sav[4];
#pragma unroll
      for (int jj = 0; jj < 4; ++jj)
        sav[jj] = *(const f32x4*)(&las[kb * 128 + wm * 64 + mf * 32 + jj * 8 + lg * 4]);
#pragma unroll
      for (int nf = 0; nf < 2; ++nf) {
        f32x16 t = {};
#pragma unroll
        for (int ks = 0; ks < 8; ++ks)
          t = __builtin_amdgcn_mfma_f32_32x32x16_fp8_fp8(af[ks], bf[nf][ks], t, 0, 0, 0);
#pragma unroll
        for (int j = 0; j < 16; ++j)
          acc[mf][nf][j] += t[j] * (sav[j >> 2][j & 3] * swd);
      }
    }
  }

  // epilogue: cw-weighted f16 tile staged in LDS (lbuf reused), coalesced store
  __syncthreads();
  _Float16* lh = (_Float16*)lbuf;
#pragma unroll
  for (int mf = 0; mf < 2; ++mf)
#pragma unroll
    for (int j = 0; j < 16; ++j) {
      int row = wm * 64 + mf * 32 + (j & 3) + ((j >> 2) * 8) + lg * 4;
      float w = lcw[row];
#pragma unroll
      for (int nf = 0; nf < 2; ++nf)
        lh[row * 128 + wn * 64 + nf * 32 + l31] = (_Float16)(acc[mf][nf][j] * w);
    }
  __syncthreads();
#pragma unroll
  for (int it = 0; it < 8; ++it) {
    int idx = it * 256 + tid;
    int row = idx >> 4, u = idx & 15;
    if (row < vrows)
      *(uint4*)((char*)yslot + ((size_t)(rowbase + row) * 1024 + nth * 128) * 2 + u * 16) =
          *(const uint4*)((const char*)lh + row * 256 + u * 16);
  }
}

// ---------- final reduction: out[t, half] = sum_k yslot[islot[t*8+k]] ----------
__global__ void k_reduce(const _Float16* __restrict__ yslot, const int* __restrict__ islot,
                         float* __restrict__ out, int half) {
  __shared__ int ls[8];
  int t = blockIdx.x;
  if (threadIdx.x < 8) ls[threadIdx.x] = islot[t * 8 + threadIdx.x];
  __syncthreads();
  int c = threadIdx.x * 4;
  float s0 = 0, s1 = 0, s2 = 0, s3 = 0;
#pragma unroll
  for (int k = 0; k < 8; ++k) {
    f16x4 v = *(const f16x4*)(yslot + (size_t)ls[k] * 1024 + c);
    s0 += (float)v[0]; s1 += (float)v[1]; s2 += (float)v[2]; s3 += (float)v[3];
  }
  f32x4 r = {s0, s1, s2, s3};
  *(f32x4*)(out + (size_t)t * 2048 + half * 1024 + c) = r;
}

extern "C" void kernel_launch(void* const* d_in, const int* in_sizes, int n_in,
                              void* d_out, int out_size, void* d_ws, size_t ws_size,
                              hipStream_t stream) {
  const float* x   = (const float*)d_in[0];
  const float* wgu = (const float*)d_in[1];
  const float* sgu = (const float*)d_in[2];
  const float* wd  = (const float*)d_in[3];
  const float* sd  = (const float*)d_in[4];
  const float* tkw = (const float*)d_in[5];
  const int*   tki = (const int*)d_in[6];
  float* out = (float*)d_out;

  char* ws = (char*)d_ws;
  size_t o = 0;
  auto alloc = [&](size_t sz) { void* p = ws + o; o = (o + sz + 255) & ~(size_t)255; return p; };
  size_t wgu_sz = (size_t)E * 2 * II * H;
  size_t ysl_sz = (size_t)NSLOT_P * II * 2;               // f16 yslot aliases wgu8
  unsigned char* x8    = (unsigned char*)alloc((size_t)T * H);
  unsigned char* wgu8  = (unsigned char*)alloc(wgu_sz > ysl_sz ? wgu_sz : ysl_sz);
  unsigned char* wd8   = (unsigned char*)alloc((size_t)E * H * II);
  unsigned char* a8    = (unsigned char*)alloc((size_t)NSLOT_P * II);
  float* xs            = (float*)alloc((size_t)T * 16 * 4);
  float* as_           = (float*)alloc((size_t)NSLOT_P * 8 * 4);
  int* counts          = (int*)alloc(128);
  int* cursor          = (int*)alloc(128);
  int* offsets         = (int*)alloc(256);
  int* tok_list        = (int*)alloc((size_t)NSLOT_P * 4);
  float* cw_list       = (float*)alloc((size_t)NSLOT_P * 4);
  int* islot           = (int*)alloc((size_t)NSLOT * 4);
  _Float16* yslot      = (_Float16*)wgu8;

  hipMemsetAsync(counts, 0, 128, stream);
  hipMemsetAsync(cursor, 0, 128, stream);

  k_quant_x<<<dim3((T * 16) / 4), dim3(256), 0, stream>>>(x, x8, xs);
  k_cvt_w_sw<<<dim3((E * 2 * II * H / 16) / 256), dim3(256), 0, stream>>>(wgu, wgu8, H / 16, E * 2 * II * H / 16);
  k_cvt_w_sw<<<dim3((E * H * II / 16) / 256), dim3(256), 0, stream>>>(wd, wd8, II / 16, E * H * II / 16);
  k_count<<<dim3(NSLOT / 256), dim3(256), 0, stream>>>(tki, counts);
  k_scan<<<dim3(1), dim3(64), 0, stream>>>(counts, offsets);
  k_fill<<<dim3(NSLOT / 256), dim3(256), 0, stream>>>(tki, tkw, offsets, cursor, tok_list, cw_list, islot);
  k_gemm1<<<dim3(E * MT1 * 8), dim3(256), 0, stream>>>(x8, xs, wgu8, sgu, offsets, counts, tok_list, a8, as_);
  k_gemm2<<<dim3(E * MT_MAX * 8), dim3(256), 0, stream>>>(a8, as_, wd8, sd, offsets, counts, cw_list, 0, yslot);
  k_reduce<<<dim3(T), dim3(256), 0, stream>>>(yslot, islot, out, 0);
  k_gemm2<<<dim3(E * MT_MAX * 8), dim3(256), 0, stream>>>(a8, as_, wd8, sd, offsets, counts, cw_list, 8, yslot);
  k_reduce<<<dim3(T), dim3(256), 0, stream>>>(yslot, islot, out, 1);
}

// Round 20
// 1568.625 us; speedup vs baseline: 2.1155x; 2.1155x over previous
//
#include <hip/hip_runtime.h>

typedef float f32x4 __attribute__((ext_vector_type(4)));
typedef float f32x16 __attribute__((ext_vector_type(16)));
typedef _Float16 f16x4 __attribute__((ext_vector_type(4)));
typedef long long i64t;

constexpr int T = 8192, H = 2048, II = 1024, E = 32, TOPK = 8;
constexpr int NSLOT = T * TOPK;
constexpr int NSLOT_P = NSLOT + E * 16 + 128;   // per-expert pad to 16 + tile-overreach slack
constexpr int MT_MAX = 32;        // 128-row blocks per expert (gemm2)
constexpr int MT1 = 64;           // 64-row blocks per expert (gemm1)

// async global->LDS, 16B per lane; LDS dest = wave-uniform base + lane*16
__device__ __forceinline__ void gload16(const unsigned char* g, unsigned char* l) {
  __builtin_amdgcn_global_load_lds((const __attribute__((address_space(1))) unsigned int*)g,
                                   (__attribute__((address_space(3))) unsigned int*)l, 16, 0, 0);
}

// ---------- LDS fp8 tile swizzle (rows x 128 bytes) ----------
// logical 8B chunk j of row r lives at physical 8B index j ^ ((r&7)<<1) ^ ((r>>3)&1).
__device__ __forceinline__ i64t frag8(const unsigned char* lds, int row, int kbyte) {
  int c8 = (kbyte >> 3) ^ ((row & 7) << 1) ^ ((row >> 3) & 1);
  return *(const i64t*)(lds + row * 128 + c8 * 8);
}
// store logical 16B chunk c of row r in swizzled image (16B XOR + 8B half-swap)
__device__ __forceinline__ void wr16c(unsigned char* lds, int r, int c, uint4 v) {
  if ((r >> 3) & 1) v = make_uint4(v.z, v.w, v.x, v.y);
  *(uint4*)(lds + r * 128 + ((c ^ (r & 7)) << 4)) = v;
}

// ---------- activation quantization (bit-exact vs reference) ----------
__global__ void k_quant_x(const float* __restrict__ x, unsigned char* __restrict__ x8,
                          float* __restrict__ xs) {
  int gw = blockIdx.x * 4 + (threadIdx.x >> 6);
  int lane = threadIdx.x & 63;
  int token = gw >> 4, kb = gw & 15;
  float2 v = *(const float2*)(x + (size_t)token * H + kb * 128 + lane * 2);
  float am = fmaxf(fabsf(v.x), fabsf(v.y));
#pragma unroll
  for (int m = 1; m <= 32; m <<= 1) am = fmaxf(am, __shfl_xor(am, m, 64));
  float scale = fmaxf(am, 1e-12f) / 448.0f;
  int pk = __builtin_amdgcn_cvt_pk_fp8_f32(v.x / scale, v.y / scale, 0, false);
  *(unsigned short*)(x8 + (size_t)token * H + kb * 128 + lane * 2) = (unsigned short)(pk & 0xffff);
  if (lane == 0) xs[token * 16 + kb] = scale;
}

// ---------- weight cast f32 -> fp8 bytes, stored in PRE-SWIZZLED (LDS-image) layout ----------
// phys 16B chunk pc of row r holds logical chunk pc^(r&7); 8B halves swapped when (r>>3)&1.
__global__ void k_cvt_w_sw(const float* __restrict__ w, unsigned char* __restrict__ w8,
                           int cpr /*16B chunks per row*/, int nchunk) {
  int i = blockIdx.x * 256 + threadIdx.x;
  if (i >= nchunk) return;
  int row = i / cpr;
  int within = i - row * cpr;
  int kb = within >> 3, pc = within & 7;
  int lc = pc ^ (row & 7);
  int sw = ((row >> 3) & 1) ? 8 : 0;
  const float* src = w + (size_t)row * ((size_t)cpr * 16) + kb * 128 + lc * 16;
  unsigned int o[4];
#pragma unroll
  for (int k = 0; k < 4; ++k) {
    int e0 = (4 * k + sw) & 15;
    f32x4 v = *(const f32x4*)(src + e0);
    int p = __builtin_amdgcn_cvt_pk_fp8_f32(v[0], v[1], 0, false);
    p = __builtin_amdgcn_cvt_pk_fp8_f32(v[2], v[3], p, true);
    o[k] = (unsigned int)p;
  }
  *(uint4*)(w8 + (size_t)i * 16) = make_uint4(o[0], o[1], o[2], o[3]);
}

// ---------- routing (per-expert ranges padded to 16 rows) ----------
__global__ void k_count(const int* __restrict__ tki, int* __restrict__ counts) {
  int i = blockIdx.x * 256 + threadIdx.x;
  if (i < NSLOT) atomicAdd(&counts[tki[i]], 1);
}
__global__ void k_scan(const int* __restrict__ counts, int* __restrict__ offsets) {
  if (threadIdx.x == 0) {
    int s = 0;
    for (int e = 0; e < E; ++e) { offsets[e] = s; s += ((counts[e] + 15) >> 4) << 4; }
    offsets[E] = s;
  }
}
__global__ void k_fill(const int* __restrict__ tki, const float* __restrict__ tkw,
                       const int* __restrict__ offsets, int* __restrict__ cursor,
                       int* __restrict__ tok_list, float* __restrict__ cw_list,
                       int* __restrict__ islot) {
  int i = blockIdx.x * 256 + threadIdx.x;
  if (i < NSLOT) {
    int e = tki[i];
    int pos = atomicAdd(&cursor[e], 1);
    int slot = offsets[e] + pos;
    tok_list[slot] = i >> 3;
    cw_list[slot] = tkw[i];
    islot[i] = slot;
  }
}

// ---------- GEMM1: 64x128 tile; B via gload_lds (dbuf), A via reg-prefetch (r11) ----------
__launch_bounds__(256, 2)
__global__ void k_gemm1(const unsigned char* __restrict__ x8, const float* __restrict__ xs,
                        const unsigned char* __restrict__ wgu8, const float* __restrict__ sgu,
                        const int* __restrict__ offsets, const int* __restrict__ counts,
                        const int* __restrict__ tok_list,
                        unsigned char* __restrict__ a8, float* __restrict__ ascale) {
  __shared__ __align__(16) unsigned char lA[64 * 128];       // 8 KB
  __shared__ __align__(16) unsigned char lBg[2][128 * 128];  // 32 KB
  __shared__ __align__(16) unsigned char lBu[2][128 * 128];  // 32 KB
  __shared__ float lsx[16 * 64];
  __shared__ int ltok[64];
  __shared__ float lamax[64 * 2];
  __shared__ float lscale[64];

  int bx = blockIdx.x;
  int e = bx >> 9, mt = (bx >> 3) & 63, nt = bx & 7;
  int off0 = offsets[e];
  int Me = counts[e];
  if (mt * 64 >= Me) return;
  int vrows = Me - mt * 64; if (vrows > 64) vrows = 64;
  int tid = threadIdx.x;

  if (tid < 64) ltok[tid] = (tid < vrows) ? tok_list[off0 + mt * 64 + tid] : -1;
  __syncthreads();

  if (tid < 128) {  // stage x scales transposed: lsx[kb][row]
    int r = tid >> 1, h = tid & 1;
    int tokr = ltok[r]; int tk = tokr < 0 ? 0 : tokr;
#pragma unroll
    for (int i = 0; i < 2; ++i) {
      f32x4 v = *(const f32x4*)(xs + (size_t)tk * 16 + h * 8 + i * 4);
#pragma unroll
      for (int j = 0; j < 4; ++j) lsx[(h * 8 + i * 4 + j) * 64 + r] = (tokr < 0) ? 0.0f : v[j];
    }
  }

  const int lane = tid & 63, wid = tid >> 6;
  const int wm = wid >> 1, wn = wid & 1;
  const int l31 = lane & 31, lg = lane >> 5;

  // A staging (register path, token-gathered; LDS-image via wr16c)
  const int ra = tid >> 2, qa = tid & 3;
  int tokA = ltok[ra] < 0 ? 0 : ltok[ra];
  const unsigned char* gA = x8 + (size_t)tokA * H + qa * 32;

  // B staging via gload_lds from PRE-SWIZZLED wgu8: linear lane->addr, linear LDS
  const int lr = lane >> 3, lc8 = lane & 7;
  const unsigned char* pG[4];
  const unsigned char* pU[4];
#pragma unroll
  for (int i = 0; i < 4; ++i) {
    int row = wid * 32 + i * 8 + lr;
    pG[i] = wgu8 + ((size_t)e * 2048 + nt * 128 + row) * H + lc8 * 16;
    pU[i] = pG[i] + (size_t)1024 * H;
  }

  // prologue: stage A(0) + issue B(0)
  {
    uint4 a0 = *(const uint4*)gA, a1 = *(const uint4*)(gA + 16);
    wr16c(lA, ra, qa * 2 + 0, a0); wr16c(lA, ra, qa * 2 + 1, a1);
  }
#pragma unroll
  for (int i = 0; i < 4; ++i) {
    gload16(pG[i], lBg[0] + wid * 4096 + i * 1024);
    gload16(pU[i], lBu[0] + wid * 4096 + i * 1024);
  }
  __syncthreads();   // drains vmcnt -> tiles 0 ready

  f32x16 aG[2] = {};
  f32x16 aU[2] = {};
  int cur = 0;

  for (int kb = 0; kb < 16; ++kb) {
    uint4 pA0, pA1;
    if (kb < 15) {   // issue next B into alternate buffers + A regs; fly under compute
#pragma unroll
      for (int i = 0; i < 4; ++i) {
        gload16(pG[i] + (kb + 1) * 128, lBg[cur ^ 1] + wid * 4096 + i * 1024);
        gload16(pU[i] + (kb + 1) * 128, lBu[cur ^ 1] + wid * 4096 + i * 1024);
      }
      pA0 = *(const uint4*)(gA + (kb + 1) * 128);
      pA1 = *(const uint4*)(gA + (kb + 1) * 128 + 16);
    }

    float swg = sgu[(e * 16 + nt) * 16 + kb];
    float swu = sgu[(e * 16 + 8 + nt) * 16 + kb];

    i64t af[8];
#pragma unroll
    for (int ks = 0; ks < 8; ++ks)
      af[ks] = frag8(lA, wm * 32 + l31, ks * 16 + lg * 8);
    f32x4 sxv[4];
#pragma unroll
    for (int jj = 0; jj < 4; ++jj)
      sxv[jj] = *(const f32x4*)(&lsx[kb * 64 + wm * 32 + jj * 8 + lg * 4]);

#pragma unroll
    for (int gu = 0; gu < 2; ++gu) {
      const unsigned char* lB = gu ? lBu[cur] : lBg[cur];
      float sw = gu ? swu : swg;
#pragma unroll
      for (int nf = 0; nf < 2; ++nf) {
        i64t bf[8];
#pragma unroll
        for (int ks = 0; ks < 8; ++ks)
          bf[ks] = frag8(lB, wn * 64 + nf * 32 + l31, ks * 16 + lg * 8);
        f32x16 t = {};
#pragma unroll
        for (int ks = 0; ks < 8; ++ks)
          t = __builtin_amdgcn_mfma_f32_32x32x16_fp8_fp8(af[ks], bf[ks], t, 0, 0, 0);
#pragma unroll
        for (int j = 0; j < 16; ++j) {
          float f = sxv[j >> 2][j & 3] * sw;
          if (gu) aU[nf][j] += t[j] * f; else aG[nf][j] += t[j] * f;
        }
      }
    }

    if (kb < 15) {
      __syncthreads();   // lA readers done (also drains vmcnt: B kb+1 arrived)
      wr16c(lA, ra, qa * 2 + 0, pA0); wr16c(lA, ra, qa * 2 + 1, pA1);
      __syncthreads();   // lA visible
      cur ^= 1;
    }
  }

  // silu(gate) * up -> aG
#pragma unroll
  for (int nf = 0; nf < 2; ++nf)
#pragma unroll
    for (int j = 0; j < 16; ++j) {
      float g = aG[nf][j], u = aU[nf][j];
      aG[nf][j] = g * (1.0f / (1.0f + expf(-g))) * u;
    }

  // per-row amax over the 128-col quant block
#pragma unroll
  for (int j = 0; j < 16; ++j) {
    float m = fmaxf(fabsf(aG[0][j]), fabsf(aG[1][j]));
#pragma unroll
    for (int msk = 1; msk <= 16; msk <<= 1) m = fmaxf(m, __shfl_xor(m, msk, 64));
    if (l31 == 0)
      lamax[(wm * 32 + (j & 3) + ((j >> 2) * 8) + lg * 4) * 2 + wn] = m;
  }
  __syncthreads();
  if (tid < 64) {
    float mm = fmaxf(lamax[tid * 2], lamax[tid * 2 + 1]);
    lscale[tid] = fmaxf(mm, 1e-12f) / 448.0f;
  }
  __syncthreads();   // lA dead -> reuse as byte staging

  // quantize into lA in PRE-SWIZZLED image (so a8 is gload_lds-ready for gemm2)
#pragma unroll
  for (int j = 0; j < 16; ++j) {
    int row = wm * 32 + (j & 3) + ((j >> 2) * 8) + lg * 4;
    float sc = lscale[row];
    int hs = ((row >> 3) & 1) ? 8 : 0;
#pragma unroll
    for (int nf = 0; nf < 2; ++nf) {
      int col = wn * 64 + nf * 32 + l31;
      int pk = __builtin_amdgcn_cvt_pk_fp8_f32(aG[nf][j] / sc, 0.0f, 0, false);
      lA[row * 128 + (((col >> 4) ^ (row & 7)) << 4) + ((col & 15) ^ hs)] = (unsigned char)(pk & 0xff);
    }
    if (row < vrows && l31 == 0 && wn == 0)
      ascale[(off0 + mt * 64 + row) * 8 + nt] = sc;
  }
  __syncthreads();
#pragma unroll
  for (int it = 0; it < 2; ++it) {
    int idx = it * 256 + tid;
    int row = idx >> 3, c = idx & 7;
    if (row < vrows)
      *(uint4*)(a8 + (size_t)(off0 + mt * 64 + row) * 1024 + nt * 128 + c * 16) =
          *(const uint4*)(lA + row * 128 + c * 16);
  }
}

// ---------- GEMM2 half-pass: A+B via gload_lds (dbuf, 1 barrier/K-step), f16 yslot ----------
__launch_bounds__(256, 2)
__global__ void k_gemm2(const unsigned char* __restrict__ a8, const float* __restrict__ ascale,
                        const unsigned char* __restrict__ wd8, const float* __restrict__ sd,
                        const int* __restrict__ offsets, const int* __restrict__ counts,
                        const float* __restrict__ cw_list,
                        int ntbase, _Float16* __restrict__ yslot) {
  __shared__ __align__(16) unsigned char lbuf[2][2][128 * 128];   // [dbuf][A/B] = 64 KB
  __shared__ float las[8 * 128];
  __shared__ float lcw[128];

  int bx = blockIdx.x;
  int e = bx >> 8, mt = (bx >> 3) & 31, nth = bx & 7;
  int nt = ntbase + nth;
  int off0 = offsets[e];
  int Me = counts[e];
  if (mt * 128 >= Me) return;
  int vrows = Me - mt * 128; if (vrows > 128) vrows = 128;
  int tid = threadIdx.x;
  const int rowbase = off0 + mt * 128;

  if (tid < 128) lcw[tid] = (tid < vrows) ? cw_list[rowbase + tid] : 0.0f;
  {
    int r = tid >> 1, h = tid & 1;
    int srow = rowbase + r; if (srow > NSLOT_P - 1) srow = NSLOT_P - 1;
    f32x4 v = *(const f32x4*)(ascale + (size_t)srow * 8 + h * 4);
#pragma unroll
    for (int j = 0; j < 4; ++j) las[(h * 4 + j) * 128 + r] = v[j];
  }

  const int lane = tid & 63, wid = tid >> 6;
  const int wm = wid >> 1, wn = wid & 1;
  const int l31 = lane & 31, lg = lane >> 5;

  const int lr = lane >> 3, lc8 = lane & 7;
  const unsigned char* pA[4];
  const unsigned char* pB[4];
#pragma unroll
  for (int i = 0; i < 4; ++i) {
    int row = wid * 32 + i * 8 + lr;
    pA[i] = a8 + (size_t)(rowbase + row) * 1024 + lc8 * 16;
    pB[i] = wd8 + ((size_t)e * 2048 + nt * 128 + row) * 1024 + lc8 * 16;
  }

  // prologue: issue tiles 0
#pragma unroll
  for (int i = 0; i < 4; ++i) {
    gload16(pA[i], lbuf[0][0] + wid * 4096 + i * 1024);
    gload16(pB[i], lbuf[0][1] + wid * 4096 + i * 1024);
  }
  __syncthreads();

  f32x16 acc[2][2] = {};
  int cur = 0;

  for (int kb = 0; kb < 8; ++kb) {
    if (kb < 7) {   // issue next tiles into alternate buffers; fly under compute
#pragma unroll
      for (int i = 0; i < 4; ++i) {
        gload16(pA[i] + (kb + 1) * 128, lbuf[cur ^ 1][0] + wid * 4096 + i * 1024);
        gload16(pB[i] + (kb + 1) * 128, lbuf[cur ^ 1][1] + wid * 4096 + i * 1024);
      }
    }
    const unsigned char* cA = lbuf[cur][0];
    const unsigned char* cB = lbuf[cur][1];
    float swd = sd[(e * 16 + nt) * 8 + kb];
    i64t bf[2][8];
#pragma unroll
    for (int nf = 0; nf < 2; ++nf)
#pragma unroll
      for (int ks = 0; ks < 8; ++ks)
        bf[nf][ks] = frag8(cB, wn * 64 + nf * 32 + l31, ks * 16 + lg * 8);
#pragma unroll
    for (int mf = 0; mf < 2; ++mf) {
      i64t af[8];
#pragma unroll
      for (int ks = 0; ks < 8; ++ks)
        af[ks] = frag8(cA, wm * 64 + mf * 32 + l31, ks * 16 + lg * 8);
      f32x4 sav[4];
#pragma unroll
      for (int jj = 0; jj < 4; ++jj)
        sav[jj] = *(const f32x4*)(&las[kb * 128 + wm * 64 + mf * 32 + jj * 8 + lg * 4]);
#pragma unroll
      for (int nf = 0; nf < 2; ++nf) {
        f32x16 t = {};
#pragma unroll
        for (int ks = 0; ks < 8; ++ks)
          t = __builtin_amdgcn_mfma_f32_32x32x16_fp8_fp8(af[ks], bf[nf][ks], t, 0, 0, 0);
#pragma unroll
        for (int j = 0; j < 16; ++j)
          acc[mf][nf][j] += t[j] * (sav[j >> 2][j & 3] * swd);
      }
    }
    __syncthreads();   // next tiles landed + readers done
    cur ^= 1;
  }

  // epilogue: cw-weighted f16 tile staged in LDS (lbuf reused), coalesced store
  _Float16* lh = (_Float16*)lbuf;
#pragma unroll
  for (int mf = 0; mf < 2; ++mf)
#pragma unroll
    for (int j = 0; j < 16; ++j) {
      int row = wm * 64 + mf * 32 + (j & 3) + ((j >> 2) * 8) + lg * 4;
      float w = lcw[row];
#pragma unroll
      for (int nf = 0; nf < 2; ++nf)
        lh[row * 128 + wn * 64 + nf * 32 + l31] = (_Float16)(acc[mf][nf][j] * w);
    }
  __syncthreads();
#pragma unroll
  for (int it = 0; it < 8; ++it) {
    int idx = it * 256 + tid;
    int row = idx >> 4, u = idx & 15;
    if (row < vrows)
      *(uint4*)((char*)yslot + ((size_t)(rowbase + row) * 1024 + nth * 128) * 2 + u * 16) =
          *(const uint4*)((const char*)lh + row * 256 + u * 16);
  }
}

// ---------- final reduction: out[t, half] = sum_k yslot[islot[t*8+k]] ----------
__global__ void k_reduce(const _Float16* __restrict__ yslot, const int* __restrict__ islot,
                         float* __restrict__ out, int half) {
  __shared__ int ls[8];
  int t = blockIdx.x;
  if (threadIdx.x < 8) ls[threadIdx.x] = islot[t * 8 + threadIdx.x];
  __syncthreads();
  int c = threadIdx.x * 4;
  float s0 = 0, s1 = 0, s2 = 0, s3 = 0;
#pragma unroll
  for (int k = 0; k < 8; ++k) {
    f16x4 v = *(const f16x4*)(yslot + (size_t)ls[k] * 1024 + c);
    s0 += (float)v[0]; s1 += (float)v[1]; s2 += (float)v[2]; s3 += (float)v[3];
  }
  f32x4 r = {s0, s1, s2, s3};
  *(f32x4*)(out + (size_t)t * 2048 + half * 1024 + c) = r;
}

extern "C" void kernel_launch(void* const* d_in, const int* in_sizes, int n_in,
                              void* d_out, int out_size, void* d_ws, size_t ws_size,
                              hipStream_t stream) {
  const float* x   = (const float*)d_in[0];
  const float* wgu = (const float*)d_in[1];
  const float* sgu = (const float*)d_in[2];
  const float* wd  = (const float*)d_in[3];
  const float* sd  = (const float*)d_in[4];
  const float* tkw = (const float*)d_in[5];
  const int*   tki = (const int*)d_in[6];
  float* out = (float*)d_out;

  char* ws = (char*)d_ws;
  size_t o = 0;
  auto alloc = [&](size_t sz) { void* p = ws + o; o = (o + sz + 255) & ~(size_t)255; return p; };
  size_t wgu_sz = (size_t)E * 2 * II * H;
  size_t ysl_sz = (size_t)NSLOT_P * II * 2;               // f16 yslot aliases wgu8
  unsigned char* x8    = (unsigned char*)alloc((size_t)T * H);
  unsigned char* wgu8  = (unsigned char*)alloc(wgu_sz > ysl_sz ? wgu_sz : ysl_sz);
  unsigned char* wd8   = (unsigned char*)alloc((size_t)E * H * II);
  unsigned char* a8    = (unsigned char*)alloc((size_t)NSLOT_P * II);
  float* xs            = (float*)alloc((size_t)T * 16 * 4);
  float* as_           = (float*)alloc((size_t)NSLOT_P * 8 * 4);
  int* counts          = (int*)alloc(128);
  int* cursor          = (int*)alloc(128);
  int* offsets         = (int*)alloc(256);
  int* tok_list        = (int*)alloc((size_t)NSLOT_P * 4);
  float* cw_list       = (float*)alloc((size_t)NSLOT_P * 4);
  int* islot           = (int*)alloc((size_t)NSLOT * 4);
  _Float16* yslot      = (_Float16*)wgu8;

  hipMemsetAsync(counts, 0, 128, stream);
  hipMemsetAsync(cursor, 0, 128, stream);

  k_quant_x<<<dim3((T * 16) / 4), dim3(256), 0, stream>>>(x, x8, xs);
  k_cvt_w_sw<<<dim3((E * 2 * II * H / 16) / 256), dim3(256), 0, stream>>>(wgu, wgu8, H / 16, E * 2 * II * H / 16);
  k_cvt_w_sw<<<dim3((E * H * II / 16) / 256), dim3(256), 0, stream>>>(wd, wd8, II / 16, E * H * II / 16);
  k_count<<<dim3(NSLOT / 256), dim3(256), 0, stream>>>(tki, counts);
  k_scan<<<dim3(1), dim3(64), 0, stream>>>(counts, offsets);
  k_fill<<<dim3(NSLOT / 256), dim3(256), 0, stream>>>(tki, tkw, offsets, cursor, tok_list, cw_list, islot);
  k_gemm1<<<dim3(E * MT1 * 8), dim3(256), 0, stream>>>(x8, xs, wgu8, sgu, offsets, counts, tok_list, a8, as_);
  k_gemm2<<<dim3(E * MT_MAX * 8), dim3(256), 0, stream>>>(a8, as_, wd8, sd, offsets, counts, cw_list, 0, yslot);
  k_reduce<<<dim3(T), dim3(256), 0, stream>>>(yslot, islot, out, 0);
  k_gemm2<<<dim3(E * MT_MAX * 8), dim3(256), 0, stream>>>(a8, as_, wd8, sd, offsets, counts, cw_list, 8, yslot);
  k_reduce<<<dim3(T), dim3(256), 0, stream>>>(yslot, islot, out, 1);
}